// Round 2
// baseline (20.369 us; speedup 1.0000x reference)
//
#include <hip/hip_runtime.h>
#include <hip/hip_bf16.h>
#include <stdint.h>

#define NN   16384
#define KK   32
#define NKE  (NN * KK)   // 524288 edges

// ---------------------------------------------------------------------------
// Wave-cooperative 64-ary lower_bound over sorted int array batch[0..n).
// All 64 lanes participate; result is wave-uniform.
// ---------------------------------------------------------------------------
__device__ __forceinline__ int wave_lower_bound(const int* __restrict__ batch,
                                                int n, int v, int lane) {
    int s = 0, e = n;                       // invariant: lower_bound in [s, e]
    while (e - s > 1) {
        int L    = e - s;
        int step = (L + 63) >> 6;
        long idx = (long)s + (long)lane * (long)step;
        bool pred = (idx < (long)e) && (batch[idx] < v);   // monotone prefix
        unsigned long long m = __ballot(pred);
        int c = __popcll(m);
        int ns = (c > 0) ? (s + (c - 1) * step + 1) : s;
        long net = (long)s + (long)c * (long)step;
        int ne = (c < 64 && net < (long)e) ? (int)net : e;
        s = ns;
        e = ne;
        if (s > e) s = e;                   // safety (should not trigger)
    }
    if (e > s && batch[s] < v) s = e;
    return s;
}

// ---------------------------------------------------------------------------
// Bitonic sort of 64 uint64 keys, one per lane, ascending across lane index.
// ---------------------------------------------------------------------------
__device__ __forceinline__ void bitonic_sort64(uint64_t& key, int lane) {
    for (int k = 2; k <= 64; k <<= 1) {
        for (int j = k >> 1; j >= 1; j >>= 1) {
            uint64_t other = __shfl_xor(key, j);
            bool keep_min = (((lane & j) == 0) == ((lane & k) == 0));
            uint64_t mn = (key < other) ? key : other;
            uint64_t mx = (key < other) ? other : key;
            key = keep_min ? mn : mx;
        }
    }
}

// Cleanup merge of a bitonic 64-sequence -> ascending.
__device__ __forceinline__ void bitonic_merge64(uint64_t& key, int lane) {
    for (int j = 32; j >= 1; j >>= 1) {
        uint64_t other = __shfl_xor(key, j);
        bool keep_min = ((lane & j) == 0);
        uint64_t mn = (key < other) ? key : other;
        uint64_t mx = (key < other) ? other : key;
        key = keep_min ? mn : mx;
    }
}

// ---------------------------------------------------------------------------
// One wave (64 lanes) per target node i.
// Sort key = (f32_bits(d2) << 32) | j  -> ascending (d2, j), matching
// jax.lax.top_k's value-then-lowest-index ordering. Invalid -> all-ones.
// Output (float32): [ row | col | weight | mask ], each NKE elements.
// ---------------------------------------------------------------------------
__global__ __launch_bounds__(256)
void radius_graph_kernel(const float* __restrict__ pos,
                         const int*   __restrict__ batch,
                         float* __restrict__ out) {
    int gid  = blockIdx.x * blockDim.x + threadIdx.x;
    int i    = gid >> 6;
    int lane = gid & 63;
    if (i >= NN) return;

    int b  = batch[i];
    int lo = wave_lower_bound(batch, NN, b, lane);
    int hi = wave_lower_bound(batch, NN, b + 1, lane);

    float xi = pos[3 * i + 0];
    float yi = pos[3 * i + 1];
    float zi = pos[3 * i + 2];
    // sq = (x*x + y*y) + z*z, plain rounding (no fma contraction)
    float sqi = __fadd_rn(__fadd_rn(__fmul_rn(xi, xi), __fmul_rn(yi, yi)),
                          __fmul_rn(zi, zi));

    auto key_for = [&](int j) -> uint64_t {
        if (j >= hi || j == i) return ~0ull;
        float xj = pos[3 * j + 0];
        float yj = pos[3 * j + 1];
        float zj = pos[3 * j + 2];
        float sqj = __fadd_rn(__fadd_rn(__fmul_rn(xj, xj), __fmul_rn(yj, yj)),
                              __fmul_rn(zj, zj));
        float dot = __fadd_rn(__fadd_rn(__fmul_rn(xi, xj), __fmul_rn(yi, yj)),
                              __fmul_rn(zi, zj));
        float d2 = __fsub_rn(__fadd_rn(sqi, sqj), __fmul_rn(2.0f, dot));
        d2 = fmaxf(d2, 0.0f);
        if (!(d2 <= 25.0f)) return ~0ull;     // CUTOFF^2
        return ((uint64_t)__float_as_uint(d2) << 32) | (uint32_t)j;
    };

    // First batch of up to 64 candidates.
    uint64_t key = key_for(lo + lane);
    bitonic_sort64(key, lane);

    // Rare: segment larger than 64 -> merge additional batches, keep 64 best.
    for (int base = lo + 64; base < hi; base += 64) {
        uint64_t k2 = key_for(base + lane);
        bitonic_sort64(k2, lane);
        uint64_t rev = __shfl(k2, 63 - lane);   // reverse second sorted list
        key = (key < rev) ? key : rev;          // lower half of bitonic merge
        bitonic_merge64(key, lane);             // re-sort ascending
    }

    // Lanes 0..31 now hold the 32 nearest (d2, j) ascending.
    int s = lane & 31;
    uint64_t ks = __shfl(key, s);               // slot-s key to both halves
    bool valid = (ks != ~0ull);
    int j   = (int)(uint32_t)ks;
    int row = valid ? j : i;
    int e   = i * KK + s;

    if (lane < 32) {
        out[e] = (float)row;                               // edge_index row
        float w = 0.0f;
        if (valid) {
            float dx = __fsub_rn(pos[3 * row + 0], xi);
            float dy = __fsub_rn(pos[3 * row + 1], yi);
            float dz = __fsub_rn(pos[3 * row + 2], zi);
            float sqd = __fadd_rn(__fadd_rn(__fmul_rn(dx, dx), __fmul_rn(dy, dy)),
                                  __fmul_rn(dz, dz));
            w = sqrtf(sqd);
        }
        out[2 * NKE + e] = w;                              // edge_weight
    } else {
        out[NKE + e]     = (float)i;                       // edge_index col
        out[3 * NKE + e] = valid ? 1.0f : 0.0f;            // edge_mask
    }
}

extern "C" void kernel_launch(void* const* d_in, const int* in_sizes, int n_in,
                              void* d_out, int out_size, void* d_ws, size_t ws_size,
                              hipStream_t stream) {
    const float* pos   = (const float*)d_in[0];
    const int*   batch = (const int*)d_in[1];
    float* out = (float*)d_out;

    // one 64-lane wave per node, 4 waves per 256-thread block
    dim3 block(256);
    dim3 grid((NN * 64) / 256);
    radius_graph_kernel<<<grid, block, 0, stream>>>(pos, batch, out);
}

// Round 3
// 13.036 us; speedup vs baseline: 1.5625x; 1.5625x over previous
//
#include <hip/hip_runtime.h>
#include <hip/hip_bf16.h>
#include <stdint.h>

#define NN   16384
#define KK   32
#define NKE  (NN * KK)   // 524288 edges

// ---------------------------------------------------------------------------
// Fallback: wave-cooperative 64-ary lower_bound (rarely used — only when a
// segment run reaches the 64-wide window edge).
// ---------------------------------------------------------------------------
__device__ __forceinline__ int wave_lower_bound(const int* __restrict__ batch,
                                                int n, int v, int lane) {
    int s = 0, e = n;
    while (e - s > 1) {
        int L    = e - s;
        int step = (L + 63) >> 6;
        long idx = (long)s + (long)lane * (long)step;
        bool pred = (idx < (long)e) && (batch[idx] < v);
        unsigned long long m = __ballot(pred);
        int c = __popcll(m);
        int ns = (c > 0) ? (s + (c - 1) * step + 1) : s;
        long net = (long)s + (long)c * (long)step;
        int ne = (c < 64 && net < (long)e) ? (int)net : e;
        s = ns; e = ne;
        if (s > e) s = e;
    }
    if (e > s && batch[s] < v) s = e;
    return s;
}

// ---------------------------------------------------------------------------
// Bitonic sort of 64 u32 keys, one per lane, ascending across lane index.
// key = (f32_bits(d2) & 0xFFFFC000) | j  -> (approx-d2, index) ascending.
// ---------------------------------------------------------------------------
__device__ __forceinline__ void bitonic_sort64_u32(unsigned& key, int lane) {
    for (int k = 2; k <= 64; k <<= 1) {
        for (int j = k >> 1; j >= 1; j >>= 1) {
            unsigned other = __shfl_xor(key, j);
            bool keep_min = (((lane & j) == 0) == ((lane & k) == 0));
            unsigned mn = key < other ? key : other;
            unsigned mx = key < other ? other : key;
            key = keep_min ? mn : mx;
        }
    }
}

__device__ __forceinline__ void bitonic_merge64_u32(unsigned& key, int lane) {
    for (int j = 32; j >= 1; j >>= 1) {
        unsigned other = __shfl_xor(key, j);
        bool keep_min = ((lane & j) == 0);
        unsigned mn = key < other ? key : other;
        unsigned mx = key < other ? other : key;
        key = keep_min ? mn : mx;
    }
}

// ---------------------------------------------------------------------------
// One wave (64 lanes) per target node i.
// Output (float32): [ row | col | weight | mask ], each NKE elements.
// ---------------------------------------------------------------------------
__global__ __launch_bounds__(256)
void radius_graph_kernel(const float* __restrict__ pos,
                         const int*   __restrict__ batch,
                         float* __restrict__ out) {
    int gid  = blockIdx.x * blockDim.x + threadIdx.x;
    int i    = gid >> 6;
    int lane = gid & 63;
    if (i >= NN) return;

    int b = batch[i];

    // --- segment bounds via 128-wide coalesced window around i ---
    int idx0 = i - 64 + lane;                       // covers [i-64, i-1]
    int v0   = batch[idx0 < 0 ? 0 : idx0];
    unsigned long long m0 = __ballot(idx0 >= 0 && v0 == b);
    int cnt_lo = (m0 == ~0ull) ? 64 : __clzll(~m0); // run length ending at i-1

    int idx1 = i + lane;                            // covers [i, i+63]
    int v1   = batch[idx1 >= NN ? NN - 1 : idx1];
    unsigned long long m1 = __ballot(idx1 < NN && v1 == b);
    unsigned long long nm1 = ~m1;
    int cnt_hi = (nm1 == 0ull) ? 64 : (__ffsll(nm1) - 1); // run from i upward

    int lo, hi;
    if (cnt_lo < 64 && cnt_hi < 64) {
        lo = i - cnt_lo;
        hi = i + cnt_hi;
    } else {                                        // segment touches window edge
        lo = wave_lower_bound(batch, NN, b, lane);
        hi = wave_lower_bound(batch, NN, b + 1, lane);
    }

    float xi = pos[3 * i + 0];
    float yi = pos[3 * i + 1];
    float zi = pos[3 * i + 2];
    float sqi = __fadd_rn(__fadd_rn(__fmul_rn(xi, xi), __fmul_rn(yi, yi)),
                          __fmul_rn(zi, zi));

    // 18 high bits of d2 (sign+exp+9 mantissa) | exact 14-bit index j.
    auto key_for = [&](int j) -> unsigned {
        if (j >= hi || j == i) return ~0u;
        float xj = pos[3 * j + 0];
        float yj = pos[3 * j + 1];
        float zj = pos[3 * j + 2];
        float sqj = __fadd_rn(__fadd_rn(__fmul_rn(xj, xj), __fmul_rn(yj, yj)),
                              __fmul_rn(zj, zj));
        float dot = __fadd_rn(__fadd_rn(__fmul_rn(xi, xj), __fmul_rn(yi, yj)),
                              __fmul_rn(zi, zj));
        float d2 = __fsub_rn(__fadd_rn(sqi, sqj), __fmul_rn(2.0f, dot));
        d2 = fmaxf(d2, 0.0f);
        if (!(d2 <= 25.0f)) return ~0u;             // exact CUTOFF^2 test
        return (__float_as_uint(d2) & 0xFFFFC000u) | (unsigned)j;
    };

    unsigned key = key_for(lo + lane);
    bitonic_sort64_u32(key, lane);

    // Rare: segment larger than 64 -> merge further 64-batches, keep best 64.
    for (int base = lo + 64; base < hi; base += 64) {
        unsigned k2 = key_for(base + lane);
        bitonic_sort64_u32(k2, lane);
        unsigned rev = __shfl(k2, 63 - lane);
        key = (key < rev) ? key : rev;
        bitonic_merge64_u32(key, lane);
    }

    // Lanes hold 64 sorted keys; slots 0..31 are the K nearest.
    int s = lane & 31;
    unsigned ks = __shfl(key, s);
    bool valid = (ks != ~0u);
    int j   = (int)(ks & 0x3FFFu);
    int row = valid ? j : i;
    int e   = i * KK + s;

    if (lane < 32) {
        out[e] = (float)row;                               // edge_index row
        float w = 0.0f;
        if (valid) {
            float dx = __fsub_rn(pos[3 * row + 0], xi);
            float dy = __fsub_rn(pos[3 * row + 1], yi);
            float dz = __fsub_rn(pos[3 * row + 2], zi);
            float sqd = __fadd_rn(__fadd_rn(__fmul_rn(dx, dx), __fmul_rn(dy, dy)),
                                  __fmul_rn(dz, dz));
            w = sqrtf(sqd);
        }
        out[2 * NKE + e] = w;                              // edge_weight
    } else {
        out[NKE + e]     = (float)i;                       // edge_index col
        out[3 * NKE + e] = valid ? 1.0f : 0.0f;            // edge_mask
    }
}

extern "C" void kernel_launch(void* const* d_in, const int* in_sizes, int n_in,
                              void* d_out, int out_size, void* d_ws, size_t ws_size,
                              hipStream_t stream) {
    const float* pos   = (const float*)d_in[0];
    const int*   batch = (const int*)d_in[1];
    float* out = (float*)d_out;

    dim3 block(256);
    dim3 grid((NN * 64) / 256);
    radius_graph_kernel<<<grid, block, 0, stream>>>(pos, batch, out);
}

// Round 4
// 12.342 us; speedup vs baseline: 1.6504x; 1.0563x over previous
//
#include <hip/hip_runtime.h>
#include <hip/hip_bf16.h>
#include <stdint.h>

#define NN   16384
#define KK   32
#define NKE  (NN * KK)   // 524288 edges

// ---------------------------------------------------------------------------
// Fallback: wave-cooperative 64-ary lower_bound (only when a segment run
// reaches the 64-wide window edge — statistically never on this dataset).
// ---------------------------------------------------------------------------
__device__ __forceinline__ int wave_lower_bound(const int* __restrict__ batch,
                                                int n, int v, int lane) {
    int s = 0, e = n;
    while (e - s > 1) {
        int L    = e - s;
        int step = (L + 63) >> 6;
        long idx = (long)s + (long)lane * (long)step;
        bool pred = (idx < (long)e) && (batch[idx] < v);
        unsigned long long m = __ballot(pred);
        int c = __popcll(m);
        int ns = (c > 0) ? (s + (c - 1) * step + 1) : s;
        long net = (long)s + (long)c * (long)step;
        int ne = (c < 64 && net < (long)e) ? (int)net : e;
        s = ns; e = ne;
        if (s > e) s = e;
    }
    if (e > s && batch[s] < v) s = e;
    return s;
}

// ---------------------------------------------------------------------------
// Bitonic sort of 64 u32 keys, one per lane, ascending across lane index.
// key = (f32_bits(d2) & 0xFFFFC000) | j  -> (approx-d2, index) ascending.
// ---------------------------------------------------------------------------
__device__ __forceinline__ void bitonic_sort64_u32(unsigned& key, int lane) {
    for (int k = 2; k <= 64; k <<= 1) {
        for (int j = k >> 1; j >= 1; j >>= 1) {
            unsigned other = __shfl_xor(key, j);
            bool keep_min = (((lane & j) == 0) == ((lane & k) == 0));
            unsigned mn = key < other ? key : other;
            unsigned mx = key < other ? other : key;
            key = keep_min ? mn : mx;
        }
    }
}

__device__ __forceinline__ void bitonic_merge64_u32(unsigned& key, int lane) {
    for (int j = 32; j >= 1; j >>= 1) {
        unsigned other = __shfl_xor(key, j);
        bool keep_min = ((lane & j) == 0);
        unsigned mn = key < other ? key : other;
        unsigned mx = key < other ? other : key;
        key = keep_min ? mn : mx;
    }
}

// ---------------------------------------------------------------------------
// One wave (64 lanes) per target node i.
// Output (float32): [ row | col | weight | mask ], each NKE elements.
// ---------------------------------------------------------------------------
__global__ __launch_bounds__(256, 8)
void radius_graph_kernel(const float* __restrict__ pos,
                         const int*   __restrict__ batch,
                         float* __restrict__ out) {
    int tid  = threadIdx.x;
    int lane = tid & 63;
    // wave-uniform node index -> SGPR, so batch[i]/pos[i] become scalar loads
    int i = __builtin_amdgcn_readfirstlane((blockIdx.x * 256 + tid) >> 6);

    int b = batch[i];

    // --- segment bounds via 128-wide coalesced window around i ---
    int idx0 = i - 64 + lane;                       // covers [i-64, i-1]
    int v0   = batch[idx0 < 0 ? 0 : idx0];
    int idx1 = i + lane;                            // covers [i, i+63]
    int v1   = batch[idx1 >= NN ? NN - 1 : idx1];

    unsigned long long m0 = __ballot(idx0 >= 0 && v0 == b);
    int cnt_lo = (m0 == ~0ull) ? 64 : __clzll(~m0); // run length ending at i-1
    unsigned long long m1 = __ballot(idx1 < NN && v1 == b);
    unsigned long long nm1 = ~m1;
    int cnt_hi = (nm1 == 0ull) ? 64 : (__ffsll(nm1) - 1); // run from i upward

    int lo, hi;
    if (cnt_lo < 64 && cnt_hi < 64) {
        lo = i - cnt_lo;
        hi = i + cnt_hi;
    } else {                                        // segment touches window edge
        lo = wave_lower_bound(batch, NN, b, lane);
        hi = wave_lower_bound(batch, NN, b + 1, lane);
    }

    float xi = pos[3 * i + 0];
    float yi = pos[3 * i + 1];
    float zi = pos[3 * i + 2];
    float sqi = __fadd_rn(__fadd_rn(__fmul_rn(xi, xi), __fmul_rn(yi, yi)),
                          __fmul_rn(zi, zi));

    // 18 high bits of d2 (sign+exp+9 mantissa) | exact 14-bit index j.
    auto key_for = [&](int j) -> unsigned {
        if (j >= hi || j == i) return ~0u;
        float xj = pos[3 * j + 0];
        float yj = pos[3 * j + 1];
        float zj = pos[3 * j + 2];
        float sqj = __fadd_rn(__fadd_rn(__fmul_rn(xj, xj), __fmul_rn(yj, yj)),
                              __fmul_rn(zj, zj));
        float dot = __fadd_rn(__fadd_rn(__fmul_rn(xi, xj), __fmul_rn(yi, yj)),
                              __fmul_rn(zi, zj));
        float d2 = __fsub_rn(__fadd_rn(sqi, sqj), __fmul_rn(2.0f, dot));
        d2 = fmaxf(d2, 0.0f);
        if (!(d2 <= 25.0f)) return ~0u;             // exact CUTOFF^2 test
        return (__float_as_uint(d2) & 0xFFFFC000u) | (unsigned)j;
    };

    unsigned key = key_for(lo + lane);
    bitonic_sort64_u32(key, lane);

    // Rare: segment larger than 64 -> merge further 64-batches, keep best 64.
    for (int base = lo + 64; base < hi; base += 64) {
        unsigned k2 = key_for(base + lane);
        bitonic_sort64_u32(k2, lane);
        unsigned rev = __shfl(k2, 63 - lane);
        key = (key < rev) ? key : rev;
        bitonic_merge64_u32(key, lane);
    }

    // Lanes hold 64 sorted keys; slots 0..31 are the K nearest.
    int s = lane & 31;
    unsigned ks = __shfl(key, s);
    bool valid = (ks != ~0u);
    int e = i * KK + s;

    if (lane < 32) {
        int row = valid ? (int)(ks & 0x3FFFu) : i;
        out[e] = (float)row;                               // edge_index row
        // weight from the key's truncated d2 (rel err 2^-10, << threshold)
        float d2s = __uint_as_float(ks & 0xFFFFC000u);
        out[2 * NKE + e] = valid ? sqrtf(d2s) : 0.0f;      // edge_weight
    } else {
        out[NKE + e]     = (float)i;                       // edge_index col
        out[3 * NKE + e] = valid ? 1.0f : 0.0f;            // edge_mask
    }
}

extern "C" void kernel_launch(void* const* d_in, const int* in_sizes, int n_in,
                              void* d_out, int out_size, void* d_ws, size_t ws_size,
                              hipStream_t stream) {
    const float* pos   = (const float*)d_in[0];
    const int*   batch = (const int*)d_in[1];
    float* out = (float*)d_out;

    dim3 block(256);
    dim3 grid((NN * 64) / 256);
    radius_graph_kernel<<<grid, block, 0, stream>>>(pos, batch, out);
}

// Round 5
// 11.565 us; speedup vs baseline: 1.7612x; 1.0671x over previous
//
#include <hip/hip_runtime.h>
#include <stdint.h>

#define NN   16384
#define KK   32
#define NKE  (NN * KK)   // 524288 edges

// ---------------------------------------------------------------------------
// Fallback: wave-cooperative 64-ary lower_bound (only when a segment run
// reaches the 128-wide window edge — statistically never on this dataset).
// ---------------------------------------------------------------------------
__device__ __forceinline__ int wave_lower_bound(const int* __restrict__ batch,
                                                int n, int v, int lane) {
    int s = 0, e = n;
    while (e - s > 1) {
        int L    = e - s;
        int step = (L + 63) >> 6;
        long idx = (long)s + (long)lane * (long)step;
        bool pred = (idx < (long)e) && (batch[idx] < v);
        unsigned long long m = __ballot(pred);
        int c = __popcll(m);
        int ns = (c > 0) ? (s + (c - 1) * step + 1) : s;
        long net = (long)s + (long)c * (long)step;
        int ne = (c < 64 && net < (long)e) ? (int)net : e;
        s = ns; e = ne;
        if (s > e) s = e;
    }
    if (e > s && batch[s] < v) s = e;
    return s;
}

// ---------------------------------------------------------------------------
// Bitonic sort of 32 u32 keys per 32-lane half (both halves concurrently).
// All shfl_xor distances <= 16 stay within the half. Ascending in each half.
// ---------------------------------------------------------------------------
__device__ __forceinline__ void bitonic_sort32_half(unsigned& key, int sub) {
    for (int k = 2; k <= 32; k <<= 1) {
        for (int j = k >> 1; j >= 1; j >>= 1) {
            unsigned other = __shfl_xor(key, j);
            bool keep_min = (((sub & j) == 0) == ((sub & k) == 0)); // k=32 -> asc
            unsigned mn = key < other ? key : other;
            unsigned mx = key < other ? other : key;
            key = keep_min ? mn : mx;
        }
    }
}

__device__ __forceinline__ void bitonic_merge32_half(unsigned& key, int sub) {
    for (int j = 16; j >= 1; j >>= 1) {
        unsigned other = __shfl_xor(key, j);
        bool keep_min = ((sub & j) == 0);
        unsigned mn = key < other ? key : other;
        unsigned mx = key < other ? other : key;
        key = keep_min ? mn : mx;
    }
}

// ---------------------------------------------------------------------------
// One wave handles TWO adjacent nodes: lanes 0-31 -> i0, lanes 32-63 -> i0+1.
// key = (f32_bits(d2) & 0xFFFFC000) | j  -> (approx-d2, index) ascending.
// Output (float32): [ row | col | weight | mask ], each NKE elements.
// ---------------------------------------------------------------------------
__global__ __launch_bounds__(256, 8)
void radius_graph_kernel(const float* __restrict__ pos,
                         const int*   __restrict__ batch,
                         float* __restrict__ out) {
    int tid  = threadIdx.x;
    int lane = tid & 63;
    int sub  = lane & 31;
    int half = lane >> 5;
    int w    = blockIdx.x * 4 + (tid >> 6);   // wave index, 0..NN/2-1
    int i0   = 2 * w;
    int i    = i0 + half;                     // this half's node

    // --- shared 128-wide window around i0: bounds for BOTH nodes ---
    int idx0 = i0 - 64 + lane;                        // [i0-64, i0-1]
    int v0   = batch[idx0 < 0 ? 0 : idx0];
    int idx1 = i0 + lane;                             // [i0, i0+63]
    int v1   = batch[idx1 >= NN ? NN - 1 : idx1];

    int b0 = __shfl(v1, 0);                           // batch[i0]
    int b1 = __shfl(v1, 1);                           // batch[i0+1]

    unsigned long long m0 = __ballot(idx0 >= 0 && v0 == b0);
    int cnt_lo = (m0 == ~0ull) ? 64 : __clzll(~m0);   // b0-run ending at i0-1
    unsigned long long m1 = __ballot(idx1 < NN && v1 == b0);
    unsigned long long nm1 = ~m1;
    int cnt_hi = (nm1 == 0ull) ? 64 : (__ffsll(nm1) - 1); // b0-run from i0 up

    // b1-run upward from i1 (only meaningful when b1 != b0)
    unsigned long long m1b = __ballot(idx1 < NN && v1 == b1);
    unsigned long long t = ~(m1b >> 1);               // bit63 always set -> t != 0
    int r1 = __ffsll(t) - 1;                          // run length from i1, <= 63

    int lo0, hi0, lo1, hi1;
    bool edge0 = (cnt_lo >= 64) || (cnt_hi >= 64);
    bool edge1 = (b1 != b0) && (r1 >= 63);
    if (!edge0 && !edge1) {                           // fast path (always, in practice)
        lo0 = i0 - cnt_lo;
        hi0 = i0 + cnt_hi;
        if (b1 == b0) { lo1 = lo0; hi1 = hi0; }
        else          { lo1 = i0 + 1; hi1 = i0 + 1 + r1; }
    } else {                                          // wave-uniform rare path
        lo0 = wave_lower_bound(batch, NN, b0, lane);
        hi0 = wave_lower_bound(batch, NN, b0 + 1, lane);
        if (b1 == b0) { lo1 = lo0; hi1 = hi0; }
        else {
            lo1 = wave_lower_bound(batch, NN, b1, lane);
            hi1 = wave_lower_bound(batch, NN, b1 + 1, lane);
        }
    }
    int lo = half ? lo1 : lo0;
    int hi = half ? hi1 : hi0;

    float xi = pos[3 * i + 0];
    float yi = pos[3 * i + 1];
    float zi = pos[3 * i + 2];
    float sqi = __fadd_rn(__fadd_rn(__fmul_rn(xi, xi), __fmul_rn(yi, yi)),
                          __fmul_rn(zi, zi));

    // 18 high bits of d2 (sign+exp+9 mantissa) | exact 14-bit index j.
    auto key_for = [&](int j) -> unsigned {
        if (j >= hi || j == i) return ~0u;
        float xj = pos[3 * j + 0];
        float yj = pos[3 * j + 1];
        float zj = pos[3 * j + 2];
        float sqj = __fadd_rn(__fadd_rn(__fmul_rn(xj, xj), __fmul_rn(yj, yj)),
                              __fmul_rn(zj, zj));
        float dot = __fadd_rn(__fadd_rn(__fmul_rn(xi, xj), __fmul_rn(yi, yj)),
                              __fmul_rn(zi, zj));
        float d2 = __fsub_rn(__fadd_rn(sqi, sqj), __fmul_rn(2.0f, dot));
        d2 = fmaxf(d2, 0.0f);
        if (!(d2 <= 25.0f)) return ~0u;               // exact CUTOFF^2 test
        return (__float_as_uint(d2) & 0xFFFFC000u) | (unsigned)j;
    };

    unsigned key = key_for(lo + sub);
    bitonic_sort32_half(key, sub);

    // Segment larger than 32: merge further 32-batches, keep best 32 sorted.
    // Batch count made wave-uniform (max of both halves) to avoid divergence;
    // overshoot batches are all-sentinel -> harmless.
    int span = (hi0 - lo0 > hi1 - lo1) ? (hi0 - lo0) : (hi1 - lo1);
    for (int off = 32; off < span; off += 32) {
        unsigned k2 = key_for(lo + off + sub);
        bitonic_sort32_half(k2, sub);
        unsigned rev = __shfl(k2, (lane & 32) | (31 - sub)); // reverse within half
        key = (key < rev) ? key : rev;                       // keep 32 smallest
        bitonic_merge32_half(key, sub);                      // re-sort ascending
    }

    // Lane `sub` of each half holds slot-`sub` of node i. All writes coalesced.
    bool valid = (key != ~0u);
    int e = i * KK + sub;
    int rowj = valid ? (int)(key & 0x3FFFu) : i;
    out[e]           = (float)rowj;                          // edge_index row
    out[NKE + e]     = (float)i;                             // edge_index col
    float d2s = __uint_as_float(key & 0xFFFFC000u);
    out[2 * NKE + e] = valid ? sqrtf(d2s) : 0.0f;            // edge_weight
    out[3 * NKE + e] = valid ? 1.0f : 0.0f;                  // edge_mask
}

extern "C" void kernel_launch(void* const* d_in, const int* in_sizes, int n_in,
                              void* d_out, int out_size, void* d_ws, size_t ws_size,
                              hipStream_t stream) {
    const float* pos   = (const float*)d_in[0];
    const int*   batch = (const int*)d_in[1];
    float* out = (float*)d_out;

    // one wave per TWO nodes: NN/2 waves, 4 waves per 256-thread block
    dim3 block(256);
    dim3 grid((NN / 2 * 64) / 256);
    radius_graph_kernel<<<grid, block, 0, stream>>>(pos, batch, out);
}